// Round 8
// baseline (64.611 us; speedup 1.0000x reference)
//
#include <hip/hip_runtime.h>
#include <math.h>

#define FRAME_LEN 512
#define HOP       256
#define NFREQ     257
#define NFREQ_PAD 288
#define NBATCH    64
#define NSAMP     160000
#define TFRAMES   624
#define EPS       1.1920928955078125e-07f

#define MT 128                 // frames per tile
#define FT 32                  // freq bins per tile
#define BK 64                  // K chunk per stage
#define NK (FRAME_LEN / BK)    // 8 K-iterations
#define NXCD 8
#define XBLKS 5000

#define AS (MT * BK)           // shorts per A buffer (8192)
#define BS (2 * FT * BK)       // shorts per B buffer (4096)

typedef __attribute__((ext_vector_type(8))) short short8;   // 8 bf16
typedef __attribute__((ext_vector_type(4))) float f32x4;    // MFMA acc

static __device__ __forceinline__ unsigned int f2bf(float f) {
    unsigned int u = __float_as_uint(f);
    return (u + 0x7fffu + ((u >> 16) & 1u)) >> 16;          // RNE to bf16
}
static __device__ __forceinline__ uint4 pack8(float4 a, float4 b) {
    uint4 r;
    r.x = f2bf(a.x) | (f2bf(a.y) << 16);
    r.y = f2bf(a.z) | (f2bf(a.w) << 16);
    r.z = f2bf(b.x) | (f2bf(b.y) << 16);
    r.w = f2bf(b.z) | (f2bf(b.w) << 16);
    return r;
}
static __device__ __forceinline__ void gload_lds16(const void* g, void* l) {
    __builtin_amdgcn_global_load_lds(
        (const __attribute__((address_space(1))) void*)g,
        (__attribute__((address_space(3))) void*)l, 16, 0, 0);
}

// ------------------------------------------------- prep: tables + x->bf16 ---
__global__ __launch_bounds__(256) void prep(const float* __restrict__ x,
                                            unsigned short* __restrict__ xbf,
                                            unsigned short* __restrict__ Wc,
                                            unsigned short* __restrict__ Ws) {
    if (blockIdx.x < XBLKS) {                   // x -> bf16, 8 elems/thread
        int i = blockIdx.x * 256 + threadIdx.x;
        const float4* src = (const float4*)x + (size_t)i * 2;
        float4 a = src[0], b = src[1];
        *(uint4*)(xbf + (size_t)i * 8) = pack8(a, b);
    } else {                                    // DFT tables, bf16, 288 rows
        int f = blockIdx.x - XBLKS;             // 0..287
        for (int n = threadIdx.x; n < FRAME_LEN; n += 256) {
            unsigned short c = 0, s = 0;
            if (f < NFREQ) {
                float w = 0.5f * (1.0f - cosf(2.0f * (float)M_PI * (float)n / (float)FRAME_LEN));
                int r = (f * n) & (FRAME_LEN - 1);
                float ang = (float)r * (2.0f * (float)M_PI / (float)FRAME_LEN);
                float sv, cv;
                sincosf(ang, &sv, &cv);
                c = (unsigned short)f2bf(cv * w);
                s = (unsigned short)f2bf(sv * w);   // i = +sin*w
            }
            Wc[f * FRAME_LEN + n] = c;
            Ws[f * FRAME_LEN + n] = s;
        }
    }
}

// ------- stft via bf16 MFMA: 3-buffer LDS pipeline, counted vmcnt ----------
__global__ __launch_bounds__(256) void stft_mfma(
    const unsigned short* __restrict__ xbf, const unsigned short* __restrict__ Wc,
    const unsigned short* __restrict__ Ws, float* __restrict__ mag)
{
    __shared__ unsigned short As[3][MT][BK];    // 48 KB, linear dest
    __shared__ unsigned short Bs[3][2][FT][BK]; // 24 KB (cos, sin)

    const int tid = threadIdx.x;
    // Bijective XCD swizzle: nwg=2808=8*351; 9 consecutive logical ids
    // (same A-tile) land on one XCD -> A fetched once per XCD L2.
    const int logical = (blockIdx.x % NXCD) * (2808 / NXCD) + blockIdx.x / NXCD;
    const int tileM = logical / 9;              // 0..311
    const int tileF = logical % 9;              // 0..8
    const int wid = tid >> 6;
    const int lane = tid & 63;
    const int lrow = lane & 15;
    const int lhi = lane >> 4;

    unsigned short* AsB = &As[0][0][0];
    unsigned short* BsB = &Bs[0][0][0][0];

    // k0-invariant per-lane staging sources (XOR swizzle on SOURCE chunk)
    const unsigned short* pA[4];
    #pragma unroll
    for (int j = 0; j < 4; j++) {
        int idx = wid * 4 + j;                  // 0..15, 8 rows each
        int row = idx * 8 + (lane >> 3);
        int m = tileM * MT + row;
        int b = m / TFRAMES;
        int t = m - b * TFRAMES;
        int chunk = (lane & 7) ^ (row & 7);
        pA[j] = xbf + (size_t)b * NSAMP + t * HOP + chunk * 8;
    }
    const unsigned short* pB[2];
    #pragma unroll
    for (int j = 0; j < 2; j++) {
        int i = wid * 2 + j;                    // 0..7: 0-3 cos, 4-7 sin
        int row = (i & 3) * 8 + (lane >> 3);
        int f = tileF * FT + row;               // < 288 (padded tables)
        int chunk = (lane & 7) ^ (row & 7);
        const unsigned short* tbl = (i & 4) ? Ws : Wc;
        pB[j] = tbl + f * FRAME_LEN + chunk * 8;
    }

    f32x4 accr[2][2] = {};
    f32x4 acci[2][2] = {};

    // ---- prologue: stage k-chunks 0 and 1 into buffers 0 and 1
    #pragma unroll
    for (int s = 0; s < 2; s++) {
        #pragma unroll
        for (int j = 0; j < 4; j++)
            gload_lds16(pA[j] + s * BK, AsB + s * AS + (wid * 4 + j) * 512);
        #pragma unroll
        for (int j = 0; j < 2; j++)
            gload_lds16(pB[j] + s * BK, BsB + s * BS + (wid * 2 + j) * 512);
    }
    asm volatile("s_waitcnt vmcnt(6)" ::: "memory");   // buf0's 6 landed
    __builtin_amdgcn_s_barrier();

    #pragma unroll
    for (int it = 0; it < NK; it++) {
        const int cur = it % 3;
        // ---- issue loads for k-chunk it+2 into buffer (it+2)%3
        if (it + 2 < NK) {
            const int nb = (it + 2) % 3;
            const int k0 = (it + 2) * BK;
            #pragma unroll
            for (int j = 0; j < 4; j++)
                gload_lds16(pA[j] + k0, AsB + nb * AS + (wid * 4 + j) * 512);
            #pragma unroll
            for (int j = 0; j < 2; j++)
                gload_lds16(pB[j] + k0, BsB + nb * BS + (wid * 2 + j) * 512);
        }
        // ---- compute current buffer (ds_read results consumed -> reads
        //      complete before the barrier; re-stage of this buffer is 2
        //      barriers away, so in-flight writes never race these reads)
        #pragma unroll
        for (int ks = 0; ks < 2; ks++) {
            short8 a[2], bc[2], bsn[2];
            const int c = (ks * 4 + lhi) ^ (lrow & 7);
            #pragma unroll
            for (int mf = 0; mf < 2; mf++)
                a[mf] = *(const short8*)(AsB + cur * AS +
                    (wid * 32 + mf * 16 + lrow) * BK + c * 8);
            #pragma unroll
            for (int nf = 0; nf < 2; nf++) {
                bc[nf]  = *(const short8*)(BsB + cur * BS +
                    (nf * 16 + lrow) * BK + c * 8);
                bsn[nf] = *(const short8*)(BsB + cur * BS + FT * BK +
                    (nf * 16 + lrow) * BK + c * 8);
            }
            #pragma unroll
            for (int mf = 0; mf < 2; mf++) {
                #pragma unroll
                for (int nf = 0; nf < 2; nf++) {
                    accr[mf][nf] = __builtin_amdgcn_mfma_f32_16x16x32_bf16(
                        a[mf], bc[nf], accr[mf][nf], 0, 0, 0);
                    acci[mf][nf] = __builtin_amdgcn_mfma_f32_16x16x32_bf16(
                        a[mf], bsn[nf], acci[mf][nf], 0, 0, 0);
                }
            }
        }
        // ---- counted wait: my 6 newest (it+2) may stay in flight; buf[it+1]
        //      is guaranteed landed. Tail falls back to full drain.
        if (it < NK - 1) {
            if (it + 2 < NK) asm volatile("s_waitcnt vmcnt(6)" ::: "memory");
            else             asm volatile("s_waitcnt vmcnt(0)" ::: "memory");
            __builtin_amdgcn_s_barrier();
        }
    }

    // ---- epilogue: mag = sqrt(r^2 + i^2), float4 over 4 consecutive t
    #pragma unroll
    for (int mf = 0; mf < 2; mf++) {
        int m0 = tileM * MT + wid * 32 + mf * 16 + lhi * 4;
        int b = m0 / TFRAMES;
        int t = m0 - b * TFRAMES;               // %4==0, run stays in batch
        #pragma unroll
        for (int nf = 0; nf < 2; nf++) {
            int f = tileF * FT + nf * 16 + lrow;
            if (f < NFREQ) {
                float4 o;
                o.x = sqrtf(accr[mf][nf][0] * accr[mf][nf][0] + acci[mf][nf][0] * acci[mf][nf][0]);
                o.y = sqrtf(accr[mf][nf][1] * accr[mf][nf][1] + acci[mf][nf][1] * acci[mf][nf][1]);
                o.z = sqrtf(accr[mf][nf][2] * accr[mf][nf][2] + acci[mf][nf][2] * acci[mf][nf][2]);
                o.w = sqrtf(accr[mf][nf][3] * accr[mf][nf][3] + acci[mf][nf][3] * acci[mf][nf][3]);
                *(float4*)(mag + ((size_t)b * NFREQ + f) * TFRAMES + t) = o;
            }
        }
    }
}

// ------------------------------------------- normalize: warp-per-row, f4 ----
__global__ __launch_bounds__(256) void normalize(const float* __restrict__ mag,
                                                 float* __restrict__ feat)
{
    const int row = blockIdx.x * 4 + (threadIdx.x >> 6);    // b*NFREQ+f
    const int lane = threadIdx.x & 63;
    const float* mp = mag + (size_t)row * TFRAMES;

    float4 v[3];
    float sum = 0.f;
    #pragma unroll
    for (int i = 0; i < 3; i++) {
        int c4 = lane + i * 64;                 // 156 float4 per row
        if (c4 < TFRAMES / 4) {
            float4 t = *(const float4*)(mp + c4 * 4);
            t.x = fmaxf(t.x, EPS); t.y = fmaxf(t.y, EPS);
            t.z = fmaxf(t.z, EPS); t.w = fmaxf(t.w, EPS);
            v[i] = t;
            sum += (t.x + t.y) + (t.z + t.w);
        } else {
            v[i] = make_float4(0.f, 0.f, 0.f, 0.f);
        }
    }
    #pragma unroll
    for (int off = 1; off < 64; off <<= 1) sum += __shfl_xor(sum, off, 64);
    const float mean = sum * (1.0f / (float)TFRAMES);

    float ssd = 0.f;
    #pragma unroll
    for (int i = 0; i < 3; i++) {
        int c4 = lane + i * 64;
        if (c4 < TFRAMES / 4) {
            float dx = v[i].x - mean, dy = v[i].y - mean;
            float dz = v[i].z - mean, dw = v[i].w - mean;
            ssd += (dx * dx + dy * dy) + (dz * dz + dw * dw);
        }
    }
    #pragma unroll
    for (int off = 1; off < 64; off <<= 1) ssd += __shfl_xor(ssd, off, 64);
    const float stdv = sqrtf(ssd * (1.0f / (float)(TFRAMES - 1)));
    const float inv = 1.0f / (stdv + EPS);

    float* fp = feat + (size_t)row * TFRAMES;
    #pragma unroll
    for (int i = 0; i < 3; i++) {
        int c4 = lane + i * 64;
        if (c4 < TFRAMES / 4) {
            float4 o;
            o.x = (v[i].x - mean) * inv; o.y = (v[i].y - mean) * inv;
            o.z = (v[i].z - mean) * inv; o.w = (v[i].w - mean) * inv;
            *(float4*)(fp + c4 * 4) = o;
        }
    }
}

// ---------------------------------------------------------------- launch ----
extern "C" void kernel_launch(void* const* d_in, const int* in_sizes, int n_in,
                              void* d_out, int out_size, void* d_ws, size_t ws_size,
                              hipStream_t stream) {
    const float* x = (const float*)d_in[0];
    unsigned short* Wc  = (unsigned short*)d_ws;            // 288*512 bf16
    unsigned short* Ws  = Wc + NFREQ_PAD * FRAME_LEN;       // 288*512 bf16
    unsigned short* xbf = Ws + NFREQ_PAD * FRAME_LEN;       // 64*160000 bf16
    float* mag  = (float*)d_out;                            // [64][257][624]
    float* feat = mag + (size_t)NBATCH * NFREQ * TFRAMES;

    prep<<<XBLKS + NFREQ_PAD, 256, 0, stream>>>(x, xbf, Wc, Ws);

    // 312 M-tiles x 9 F-tiles, linearized + XCD-swizzled in-kernel
    stft_mfma<<<312 * 9, 256, 0, stream>>>(xbf, Wc, Ws, mag);

    normalize<<<NBATCH * NFREQ / 4, 256, 0, stream>>>(mag, feat);
}